// Round 3
// baseline (11.787 us; speedup 1.0000x reference)
//
#include <hip/hip_runtime.h>
#include <hip/hip_bf16.h>

// Shapes (fixed by the reference):
//   input:       [B=32, S=2048, H=1024] float32
//   number_mask: [B=32, S=2048] int
//   max_number:  scalar 20 -> J = 20 labels (1..20)
//   output:      [B, J, 2H] float32
#define B_DIM 32
#define S_DIM 2048
#define H_DIM 1024
#define J_DIM 20

// One block of 512 per (b, j). Scan mask row (int4: one load/thread) for
// first/last occurrence of label j+1, single-barrier block reduce, then
// each thread moves exactly one float4: t<256 -> first-row, t>=256 -> last-row.
__global__ __launch_bounds__(512) void aware_fused_kernel(
        const float* __restrict__ in,
        const int* __restrict__ mask,
        float* __restrict__ out) {
    const int bj    = blockIdx.x;        // b * J + j
    const int b     = bj / J_DIM;
    const int label = bj - b * J_DIM + 1;
    const int t     = threadIdx.x;       // 512 threads = 8 waves

    // --- scan: one int4 per thread covers all 2048 entries ---
    const int4* m4 = reinterpret_cast<const int4*>(mask + (size_t)b * S_DIM);
    const int4 v   = m4[t];
    const int  s0  = t * 4;
    int lmin = S_DIM;
    int lmax = -1;
    if (v.x == label) { lmin = s0;               lmax = s0;     }
    if (v.y == label) { lmin = min(lmin, s0 + 1); lmax = s0 + 1; }
    if (v.z == label) { lmin = min(lmin, s0 + 2); lmax = s0 + 2; }
    if (v.w == label) { lmin = min(lmin, s0 + 3); lmax = s0 + 3; }

    // --- wave (64-lane) reduce ---
    #pragma unroll
    for (int off = 32; off > 0; off >>= 1) {
        lmin = min(lmin, __shfl_down(lmin, off, 64));
        lmax = max(lmax, __shfl_down(lmax, off, 64));
    }

    // --- cross-wave combine: one barrier, broadcast reads ---
    __shared__ int swf[8], swl[8];
    if ((t & 63) == 0) {
        swf[t >> 6] = lmin;
        swl[t >> 6] = lmax;
    }
    __syncthreads();
    int f = swf[0], l = swl[0];
    #pragma unroll
    for (int w = 1; w < 8; ++w) {
        f = min(f, swf[w]);
        l = max(l, swl[w]);
    }
    const bool exists = (f < S_DIM);

    // --- gather: one float4 per thread ---
    float4* o = reinterpret_cast<float4*>(out + (size_t)bj * (2 * H_DIM));
    if (exists) {
        const int row = (t < 256) ? f : l;
        const float4* src = reinterpret_cast<const float4*>(
            in + ((size_t)b * S_DIM + row) * H_DIM);
        o[t] = src[t & 255];
    } else {
        float4 z; z.x = 0.f; z.y = 0.f; z.z = 0.f; z.w = 0.f;
        o[t] = z;
    }
}

extern "C" void kernel_launch(void* const* d_in, const int* in_sizes, int n_in,
                              void* d_out, int out_size, void* d_ws, size_t ws_size,
                              hipStream_t stream) {
    const float* input = (const float*)d_in[0];
    const int*   mask  = (const int*)d_in[1];
    float*       out   = (float*)d_out;

    aware_fused_kernel<<<B_DIM * J_DIM, 512, 0, stream>>>(input, mask, out);
}